// Round 15
// baseline (109.680 us; speedup 1.0000x reference)
//
#include <hip/hip_runtime.h>
#include <hip/hip_bf16.h>

typedef __attribute__((ext_vector_type(8))) short short8;
typedef __attribute__((ext_vector_type(4))) float f32x4;
typedef __attribute__((ext_vector_type(16))) float f32x16;
typedef unsigned short u16;
typedef unsigned int u32;

static __device__ __forceinline__ u16 f2b(float f) {
  __hip_bfloat16 h = __float2bfloat16(f);
  return __builtin_bit_cast(u16, h);
}
static __device__ __forceinline__ float b2f(u16 v) {
  return __builtin_bit_cast(float, ((u32)v) << 16);
}
static __device__ __forceinline__ u32 pk2(float lo, float hi) {
  return (u32)f2b(lo) | ((u32)f2b(hi) << 16);
}
static __device__ __forceinline__ u32 cvtpk(float lo, float hi) {
  u32 r;
  asm("v_cvt_pk_bf16_f32 %0, %1, %2" : "=v"(r) : "v"(lo), "v"(hi));
  return r;
}

static __device__ __forceinline__ void gload16(const void* g, void* l) {
  __builtin_amdgcn_global_load_lds((const __attribute__((address_space(1))) void*)g,
                                   (__attribute__((address_space(3))) void*)l, 16, 0, 0);
}

// Raw s_barrier has no compiler memory fence; add zero-cost scheduler+IR fences.
static __device__ __forceinline__ void barrier_fenced() {
  __builtin_amdgcn_sched_barrier(0);
  asm volatile("" ::: "memory");
  __builtin_amdgcn_s_barrier();
  __builtin_amdgcn_sched_barrier(0);
  asm volatile("" ::: "memory");
}

// ---------------- merged prep: x->bf16 | W_attn K-slice transpose | W_proj transpose ------
__global__ __launch_bounds__(256) void prep(const float4* __restrict__ x4,
                                            uint2* __restrict__ xb,
                                            const float* __restrict__ W_attn,
                                            u16* __restrict__ Wkt,
                                            const float* __restrict__ W_proj,
                                            u16* __restrict__ Wpt) {
  __shared__ u16 tile[32][33];
  int bid = blockIdx.x, t = threadIdx.x;
  if (bid < 4096) {
    int i = bid * 256 + t;
    float4 v = x4[i];
    uint2 o;
    o.x = pk2(v.x, v.y);
    o.y = pk2(v.z, v.w);
    xb[i] = o;
    return;
  }
  const float* in;
  u16* out;
  int in_rs, col_off, blk;
  if (bid < 5120) {
    in = W_attn; out = Wkt; in_rs = 3072; col_off = 1024; blk = bid - 4096;
  } else {
    in = W_proj; out = Wpt; in_rs = 1024; col_off = 0; blk = bid - 5120;
  }
  int tx = t & 31, ty = t >> 5;
  int r0 = (blk >> 5) * 32, c0 = (blk & 31) * 32;
#pragma unroll
  for (int i = 0; i < 4; ++i) {
    int r = r0 + ty + i * 8;
    tile[ty + i * 8][tx] = f2b(in[(size_t)r * in_rs + col_off + c0 + tx]);
  }
  __syncthreads();
#pragma unroll
  for (int i = 0; i < 4; ++i) {
    int c = c0 + ty + i * 8;
    out[(size_t)c * 1024 + r0 + tx] = tile[tx][ty + i * 8];
  }
}

// ---------------- GEMM: C[M][N] = A[M][K] * Bt[N][K]^T + bias (r13 proven) ----------------
template <int MODE>
__global__ __launch_bounds__(256) void gemm_bias(const u16* __restrict__ A,
                                                 const u16* __restrict__ Bt,
                                                 const float* __restrict__ bias,
                                                 void* __restrict__ Cp, u16* __restrict__ Ktp,
                                                 int M, int N, int K) {
  __shared__ char lds[2][16384];  // per buf: A 64x128B | B 64x128B
  int tid = threadIdx.x, lane = tid & 63, wid = tid >> 6;
  int lr = lane & 15, lh = lane >> 4;
  int rb = blockIdx.x;
  int bid = (rb & 7) * 128 + (rb >> 3);  // XCD chunking (1024 = 8 x 128)
  int m0 = (bid >> 4) << 6, n0 = (bid & 15) << 6;
  int wm = wid >> 1, wn = wid & 1;
  f32x4 acc[2][2] = {};
  int srow = lane >> 3;
  int scol = ((lane & 7) << 4) ^ (srow << 4);
  const char* Ab = (const char*)A;
  const char* Bb = (const char*)Bt;
  const int NT = K >> 6;

  auto stage = [&](char* buf, int k0) {
    char* lA = buf;
    char* lB = buf + 8192;
#pragma unroll
    for (int j = 0; j < 2; ++j) {
      int rg = wid * 16 + j * 8;
      gload16(Ab + ((size_t)(m0 + rg + srow) * K + k0) * 2 + scol, lA + rg * 128);
      gload16(Bb + ((size_t)(n0 + rg + srow) * K + k0) * 2 + scol, lB + rg * 128);
    }
  };

  stage(lds[0], 0);
  for (int t = 0; t < NT; ++t) {
    asm volatile("s_waitcnt vmcnt(0) lgkmcnt(0)" ::: "memory");
    barrier_fenced();
    if (t + 1 < NT) stage(lds[(t + 1) & 1], (t + 1) << 6);
    char* lA = lds[t & 1];
    char* lB = lA + 8192;
    short8 af[2][2], bfr[2][2];
#pragma unroll
    for (int mi = 0; mi < 2; ++mi)
#pragma unroll
      for (int ks = 0; ks < 2; ++ks) {
        int row = wm * 32 + mi * 16 + lr;
        af[mi][ks] = *(const short8*)(lA + row * 128 + ((ks * 64 + lh * 16) ^ ((row & 7) << 4)));
      }
#pragma unroll
    for (int ni = 0; ni < 2; ++ni)
#pragma unroll
      for (int ks = 0; ks < 2; ++ks) {
        int row = wn * 32 + ni * 16 + lr;
        bfr[ni][ks] = *(const short8*)(lB + row * 128 + ((ks * 64 + lh * 16) ^ ((row & 7) << 4)));
      }
    __builtin_amdgcn_s_setprio(1);
#pragma unroll
    for (int ks = 0; ks < 2; ++ks)
#pragma unroll
      for (int mi = 0; mi < 2; ++mi)
#pragma unroll
        for (int ni = 0; ni < 2; ++ni)
          acc[mi][ni] = __builtin_amdgcn_mfma_f32_16x16x32_bf16(af[mi][ks], bfr[ni][ks],
                                                                acc[mi][ni], 0, 0, 0);
    __builtin_amdgcn_s_setprio(0);
  }
#pragma unroll
  for (int mi = 0; mi < 2; ++mi)
#pragma unroll
    for (int ni = 0; ni < 2; ++ni) {
      int col = n0 + wn * 32 + ni * 16 + lr;
      float bz = bias[col];
      int row0 = m0 + wm * 32 + mi * 16 + lh * 4;
      if (MODE == 1) {
#pragma unroll
        for (int r = 0; r < 4; ++r)
          ((float*)Cp)[(size_t)(row0 + r) * N + col] = acc[mi][ni][r] + bz;
      } else {
        ushort4 q;
        u16* qa = (u16*)&q;
#pragma unroll
        for (int r = 0; r < 4; ++r) {
          u16 v = f2b(acc[mi][ni][r] + bz);
          qa[r] = v;
          ((u16*)Cp)[(size_t)(row0 + r) * N + col] = v;
        }
        *(ushort4*)(Ktp + ((size_t)((row0 >> 11) * 1024 + col)) * 2048 + (row0 & 2047)) = q;
      }
    }
}

// ---------------- flash attention: 2-wave blocks x 64 q-rows/wave (ILP + TLP) -------------
// grid 512 (XCD-chunked) x 128 threads: 16 blocks per (b,h), 128 q-rows/block.
// Per wave: two independent QK->softmax->PV chains (r14's 1.72x per-wave efficiency);
// 4 blocks/CU (VGPR-capped) = 8 waves/CU in 4 independent barrier domains (2x r13).
__global__ __launch_bounds__(128, 2) void flash_attn(const u16* __restrict__ Kb,
                                                     const u16* __restrict__ Kt,
                                                     u16* __restrict__ AO) {
  __shared__ char kv[2][16384];  // per buf: K [64k][128B] | V [64d][128B]
  const float S2 = 0.125f * 1.44269504088896340736f;
  int tid = threadIdx.x, lane = tid & 63, wid = tid >> 6;  // wid 0..1
  int ql = lane & 31, half = lane >> 5;
  int rb = blockIdx.x;
  int bid = (rb & 7) * 64 + (rb >> 3);  // XCD chunking (512 = 8 x 64)
  int qt = bid & 15, h = (bid >> 4) & 15, b = bid >> 8;
  int qbase = b * 2048 + qt * 128 + wid * 64;  // Q-block A: +0..31, B: +32..63
  int hc = h * 64;
  short8 qfrA[4], qfrB[4];
#pragma unroll
  for (int ds = 0; ds < 4; ++ds) {
    short8 rawA = *(const short8*)(Kb + (size_t)(qbase + ql) * 1024 + hc + ds * 16 + half * 8);
    short8 rawB =
        *(const short8*)(Kb + (size_t)(qbase + 32 + ql) * 1024 + hc + ds * 16 + half * 8);
    short8 qa, qb2;
#pragma unroll
    for (int j = 0; j < 8; ++j) {
      qa[j] = (short)f2b(b2f((u16)rawA[j]) * S2);
      qb2[j] = (short)f2b(b2f((u16)rawB[j]) * S2);
    }
    qfrA[ds] = qa;
    qfrB[ds] = qb2;
  }
  const short8 ones = {0x3F80, 0x3F80, 0x3F80, 0x3F80, 0x3F80, 0x3F80, 0x3F80, 0x3F80};
  f32x16 accA0 = {}, accA1 = {}, accAs = {};
  f32x16 accB0 = {}, accB1 = {}, accBs = {};
  int srow = lane >> 3;
  int scol = ((lane & 7) << 4) ^ (srow << 4);
  const char* Kbase = (const char*)Kb + (size_t)(b * 2048) * 2048 + hc * 2;
  const char* Vbase = (const char*)Kt + (size_t)((b * 16 + h) * 64) * 4096;

  // 2 waves split the 8 row-groups of each of K and V (r11-proven arrangement)
  auto stage = [&](char* buf, int kt) {
    const char* kp = Kbase + (size_t)(kt * 64) * 2048;
    const char* vp = Vbase + (size_t)(kt * 128);
    char* lk = buf;
    char* lv = buf + 8192;
#pragma unroll
    for (int j = 0; j < 4; ++j) {
      int grp = j * 2 + wid;  // 0..7
      int row = grp * 8 + srow;
      gload16(kp + (size_t)row * 2048 + scol, lk + grp * 8 * 128);
      gload16(vp + (size_t)row * 4096 + scol, lv + grp * 8 * 128);
    }
  };

  auto softmax_pack = [&](const f32x16& s0, const f32x16& s1, short8 pa[4]) {
    float p[32];
#pragma unroll
    for (int i = 0; i < 16; ++i) p[i] = __builtin_amdgcn_exp2f(s0[i]);
#pragma unroll
    for (int i = 0; i < 16; ++i) p[16 + i] = __builtin_amdgcn_exp2f(s1[i]);
    u32 w0[8], w1[8];
#pragma unroll
    for (int g = 0; g < 8; ++g) {
      int idx = (g >> 2) * 16 + (g & 3) * 4;
      w0[g] = cvtpk(p[idx], p[idx + 1]);
      w1[g] = cvtpk(p[idx + 2], p[idx + 3]);
    }
#pragma unroll
    for (int ks = 0; ks < 4; ++ks) {
      u32 a0 = w0[2 * ks], b0 = w0[2 * ks + 1];
      u32 a1 = w1[2 * ks], b1 = w1[2 * ks + 1];
      asm volatile("v_permlane32_swap_b32 %0, %1" : "+v"(a0), "+v"(b0));
      asm volatile("v_permlane32_swap_b32 %0, %1" : "+v"(a1), "+v"(b1));
      uint4 words = {a0, a1, b0, b1};
      pa[ks] = __builtin_bit_cast(short8, words);
    }
  };

  stage(kv[0], 0);
  for (int kt = 0; kt < 32; ++kt) {
    asm volatile("s_waitcnt vmcnt(0) lgkmcnt(0)" ::: "memory");
    barrier_fenced();
    if (kt + 1 < 32) stage(kv[(kt + 1) & 1], kt + 1);
    const char* lk = kv[kt & 1];
    const char* lv = lk + 8192;
    // shared K fragments
    short8 kf[2][4];
#pragma unroll
    for (int kb = 0; kb < 2; ++kb)
#pragma unroll
      for (int ds = 0; ds < 4; ++ds) {
        int row = kb * 32 + ql;
        kf[kb][ds] = *(const short8*)(lk + row * 128 + ((ds * 32 + half * 16) ^ ((row & 7) << 4)));
      }
    // QK for both Q-blocks (independent chains)
    f32x16 sA0 = {}, sA1 = {}, sB0 = {}, sB1 = {};
    __builtin_amdgcn_s_setprio(1);
#pragma unroll
    for (int ds = 0; ds < 4; ++ds) {
      sA0 = __builtin_amdgcn_mfma_f32_32x32x16_bf16(kf[0][ds], qfrA[ds], sA0, 0, 0, 0);
      sB0 = __builtin_amdgcn_mfma_f32_32x32x16_bf16(kf[0][ds], qfrB[ds], sB0, 0, 0, 0);
      sA1 = __builtin_amdgcn_mfma_f32_32x32x16_bf16(kf[1][ds], qfrA[ds], sA1, 0, 0, 0);
      sB1 = __builtin_amdgcn_mfma_f32_32x32x16_bf16(kf[1][ds], qfrB[ds], sB1, 0, 0, 0);
    }
    __builtin_amdgcn_s_setprio(0);
    // softmax+pack, both blocks (independent chains interleave)
    short8 paA[4], paB[4];
    softmax_pack(sA0, sA1, paA);
    softmax_pack(sB0, sB1, paB);
    // shared V fragments
    short8 vf0[4], vf1[4];
#pragma unroll
    for (int ks = 0; ks < 4; ++ks) {
      int row0 = ql, row1 = 32 + ql;
      vf0[ks] = *(const short8*)(lv + row0 * 128 + ((ks * 32 + half * 16) ^ ((row0 & 7) << 4)));
      vf1[ks] = *(const short8*)(lv + row1 * 128 + ((ks * 32 + half * 16) ^ ((row1 & 7) << 4)));
    }
    // PV + row-sums, both blocks
    __builtin_amdgcn_s_setprio(1);
#pragma unroll
    for (int ks = 0; ks < 4; ++ks) {
      accA0 = __builtin_amdgcn_mfma_f32_32x32x16_bf16(paA[ks], vf0[ks], accA0, 0, 0, 0);
      accB0 = __builtin_amdgcn_mfma_f32_32x32x16_bf16(paB[ks], vf0[ks], accB0, 0, 0, 0);
      accA1 = __builtin_amdgcn_mfma_f32_32x32x16_bf16(paA[ks], vf1[ks], accA1, 0, 0, 0);
      accB1 = __builtin_amdgcn_mfma_f32_32x32x16_bf16(paB[ks], vf1[ks], accB1, 0, 0, 0);
      accAs = __builtin_amdgcn_mfma_f32_32x32x16_bf16(paA[ks], ones, accAs, 0, 0, 0);
      accBs = __builtin_amdgcn_mfma_f32_32x32x16_bf16(paB[ks], ones, accBs, 0, 0, 0);
    }
    __builtin_amdgcn_s_setprio(0);
  }
#pragma unroll
  for (int reg = 0; reg < 16; ++reg) {
    int ridx = (reg & 3) + 8 * (reg >> 2) + 4 * half;
    int growA = qbase + ridx;
    int growB = qbase + 32 + ridx;
    float ivA = __builtin_amdgcn_rcpf(accAs[reg]);
    float ivB = __builtin_amdgcn_rcpf(accBs[reg]);
    AO[(size_t)growA * 1024 + hc + ql] = f2b(accA0[reg] * ivA);
    AO[(size_t)growA * 1024 + hc + 32 + ql] = f2b(accA1[reg] * ivA);
    AO[(size_t)growB * 1024 + hc + ql] = f2b(accB0[reg] * ivB);
    AO[(size_t)growB * 1024 + hc + 32 + ql] = f2b(accB1[reg] * ivB);
  }
}

// ---------------- launch ----------------

extern "C" void kernel_launch(void* const* d_in, const int* in_sizes, int n_in, void* d_out,
                              int out_size, void* d_ws, size_t ws_size, hipStream_t stream) {
  const float* x = (const float*)d_in[0];
  const float* W_attn = (const float*)d_in[1];
  const float* b_attn = (const float*)d_in[2];
  const float* W_proj = (const float*)d_in[3];
  const float* b_proj = (const float*)d_in[4];
  float* out = (float*)d_out;
  char* ws = (char*)d_ws;
  u16* xb = (u16*)(ws);
  u16* Kb = (u16*)(ws + 8388608);
  u16* Kt = (u16*)(ws + 16777216);
  u16* Wkt = (u16*)(ws + 25165824);
  u16* Wpt = (u16*)(ws + 27262976);

  prep<<<6144, 256, 0, stream>>>((const float4*)x, (uint2*)xb, W_attn, Wkt, W_proj, Wpt);
  gemm_bias<0><<<1024, 256, 0, stream>>>(xb, Wkt, b_attn + 1024, (void*)Kb, Kt, 4096, 1024, 1024);
  u16* AO = xb;
  flash_attn<<<512, 128, 0, stream>>>(Kb, Kt, AO);
  gemm_bias<1><<<1024, 256, 0, stream>>>(AO, Wpt, b_proj, (void*)out, nullptr, 4096, 1024, 1024);
}

// Round 16
// 97.150 us; speedup vs baseline: 1.1290x; 1.1290x over previous
//
#include <hip/hip_runtime.h>
#include <hip/hip_bf16.h>

typedef __attribute__((ext_vector_type(8))) short short8;
typedef __attribute__((ext_vector_type(4))) float f32x4;
typedef __attribute__((ext_vector_type(16))) float f32x16;
typedef unsigned short u16;
typedef unsigned int u32;

static __device__ __forceinline__ u16 f2b(float f) {
  __hip_bfloat16 h = __float2bfloat16(f);
  return __builtin_bit_cast(u16, h);
}
static __device__ __forceinline__ float b2f(u16 v) {
  return __builtin_bit_cast(float, ((u32)v) << 16);
}
static __device__ __forceinline__ u32 pk2(float lo, float hi) {
  return (u32)f2b(lo) | ((u32)f2b(hi) << 16);
}
static __device__ __forceinline__ u32 cvtpk(float lo, float hi) {
  u32 r;
  asm("v_cvt_pk_bf16_f32 %0, %1, %2" : "=v"(r) : "v"(lo), "v"(hi));
  return r;
}

static __device__ __forceinline__ void gload16(const void* g, void* l) {
  __builtin_amdgcn_global_load_lds((const __attribute__((address_space(1))) void*)g,
                                   (__attribute__((address_space(3))) void*)l, 16, 0, 0);
}

// Raw s_barrier has no compiler memory fence; add zero-cost scheduler+IR fences.
static __device__ __forceinline__ void barrier_fenced() {
  __builtin_amdgcn_sched_barrier(0);
  asm volatile("" ::: "memory");
  __builtin_amdgcn_s_barrier();
  __builtin_amdgcn_sched_barrier(0);
  asm volatile("" ::: "memory");
}

// ---------------- merged prep: x->bf16 | W_attn K-slice transpose | W_proj transpose ------
__global__ __launch_bounds__(256) void prep(const float4* __restrict__ x4,
                                            uint2* __restrict__ xb,
                                            const float* __restrict__ W_attn,
                                            u16* __restrict__ Wkt,
                                            const float* __restrict__ W_proj,
                                            u16* __restrict__ Wpt) {
  __shared__ u16 tile[32][33];
  int bid = blockIdx.x, t = threadIdx.x;
  if (bid < 4096) {
    int i = bid * 256 + t;
    float4 v = x4[i];
    uint2 o;
    o.x = pk2(v.x, v.y);
    o.y = pk2(v.z, v.w);
    xb[i] = o;
    return;
  }
  const float* in;
  u16* out;
  int in_rs, col_off, blk;
  if (bid < 5120) {
    in = W_attn; out = Wkt; in_rs = 3072; col_off = 1024; blk = bid - 4096;
  } else {
    in = W_proj; out = Wpt; in_rs = 1024; col_off = 0; blk = bid - 5120;
  }
  int tx = t & 31, ty = t >> 5;
  int r0 = (blk >> 5) * 32, c0 = (blk & 31) * 32;
#pragma unroll
  for (int i = 0; i < 4; ++i) {
    int r = r0 + ty + i * 8;
    tile[ty + i * 8][tx] = f2b(in[(size_t)r * in_rs + col_off + c0 + tx]);
  }
  __syncthreads();
#pragma unroll
  for (int i = 0; i < 4; ++i) {
    int c = c0 + ty + i * 8;
    out[(size_t)c * 1024 + r0 + tx] = tile[tx][ty + i * 8];
  }
}

// ---------------- GEMM: C[M][N] = A[M][K] * Bt[N][K]^T + bias (r13 proven) ----------------
template <int MODE>
__global__ __launch_bounds__(256) void gemm_bias(const u16* __restrict__ A,
                                                 const u16* __restrict__ Bt,
                                                 const float* __restrict__ bias,
                                                 void* __restrict__ Cp, u16* __restrict__ Ktp,
                                                 int M, int N, int K) {
  __shared__ char lds[2][16384];  // per buf: A 64x128B | B 64x128B
  int tid = threadIdx.x, lane = tid & 63, wid = tid >> 6;
  int lr = lane & 15, lh = lane >> 4;
  int rb = blockIdx.x;
  int bid = (rb & 7) * 128 + (rb >> 3);  // XCD chunking (1024 = 8 x 128)
  int m0 = (bid >> 4) << 6, n0 = (bid & 15) << 6;
  int wm = wid >> 1, wn = wid & 1;
  f32x4 acc[2][2] = {};
  int srow = lane >> 3;
  int scol = ((lane & 7) << 4) ^ (srow << 4);
  const char* Ab = (const char*)A;
  const char* Bb = (const char*)Bt;
  const int NT = K >> 6;

  auto stage = [&](char* buf, int k0) {
    char* lA = buf;
    char* lB = buf + 8192;
#pragma unroll
    for (int j = 0; j < 2; ++j) {
      int rg = wid * 16 + j * 8;
      gload16(Ab + ((size_t)(m0 + rg + srow) * K + k0) * 2 + scol, lA + rg * 128);
      gload16(Bb + ((size_t)(n0 + rg + srow) * K + k0) * 2 + scol, lB + rg * 128);
    }
  };

  stage(lds[0], 0);
  for (int t = 0; t < NT; ++t) {
    asm volatile("s_waitcnt vmcnt(0) lgkmcnt(0)" ::: "memory");
    barrier_fenced();
    if (t + 1 < NT) stage(lds[(t + 1) & 1], (t + 1) << 6);
    char* lA = lds[t & 1];
    char* lB = lA + 8192;
    short8 af[2][2], bfr[2][2];
#pragma unroll
    for (int mi = 0; mi < 2; ++mi)
#pragma unroll
      for (int ks = 0; ks < 2; ++ks) {
        int row = wm * 32 + mi * 16 + lr;
        af[mi][ks] = *(const short8*)(lA + row * 128 + ((ks * 64 + lh * 16) ^ ((row & 7) << 4)));
      }
#pragma unroll
    for (int ni = 0; ni < 2; ++ni)
#pragma unroll
      for (int ks = 0; ks < 2; ++ks) {
        int row = wn * 32 + ni * 16 + lr;
        bfr[ni][ks] = *(const short8*)(lB + row * 128 + ((ks * 64 + lh * 16) ^ ((row & 7) << 4)));
      }
    __builtin_amdgcn_s_setprio(1);
#pragma unroll
    for (int ks = 0; ks < 2; ++ks)
#pragma unroll
      for (int mi = 0; mi < 2; ++mi)
#pragma unroll
        for (int ni = 0; ni < 2; ++ni)
          acc[mi][ni] = __builtin_amdgcn_mfma_f32_16x16x32_bf16(af[mi][ks], bfr[ni][ks],
                                                                acc[mi][ni], 0, 0, 0);
    __builtin_amdgcn_s_setprio(0);
  }
#pragma unroll
  for (int mi = 0; mi < 2; ++mi)
#pragma unroll
    for (int ni = 0; ni < 2; ++ni) {
      int col = n0 + wn * 32 + ni * 16 + lr;
      float bz = bias[col];
      int row0 = m0 + wm * 32 + mi * 16 + lh * 4;
      if (MODE == 1) {
#pragma unroll
        for (int r = 0; r < 4; ++r)
          ((float*)Cp)[(size_t)(row0 + r) * N + col] = acc[mi][ni][r] + bz;
      } else {
        ushort4 q;
        u16* qa = (u16*)&q;
#pragma unroll
        for (int r = 0; r < 4; ++r) {
          u16 v = f2b(acc[mi][ni][r] + bz);
          qa[r] = v;
          ((u16*)Cp)[(size_t)(row0 + r) * N + col] = v;
        }
        *(ushort4*)(Ktp + ((size_t)((row0 >> 11) * 1024 + col)) * 2048 + (row0 & 2047)) = q;
      }
    }
}

// ---------------- flash attention: 2-wave blocks x 64 q-rows/wave (ILP + TLP) -------------
// grid 512 (XCD-chunked) x 128 threads: 16 blocks per (b,h), 128 q-rows/block.
// NO min-waves launch bound: the dual-chain body needs ~190 VGPRs at its QK peak;
// forcing 128 (r15) spilled to scratch and collapsed VALUBusy 38->19%. At ~172-190
// VGPR the HW still allows 2 waves/SIMD, and 2-wave blocks give 2 independent
// barrier domains per CU (vs 1 in r14).
__global__ __launch_bounds__(128) void flash_attn(const u16* __restrict__ Kb,
                                                  const u16* __restrict__ Kt,
                                                  u16* __restrict__ AO) {
  __shared__ char kv[2][16384];  // per buf: K [64k][128B] | V [64d][128B]
  const float S2 = 0.125f * 1.44269504088896340736f;
  int tid = threadIdx.x, lane = tid & 63, wid = tid >> 6;  // wid 0..1
  int ql = lane & 31, half = lane >> 5;
  int rb = blockIdx.x;
  int bid = (rb & 7) * 64 + (rb >> 3);  // XCD chunking (512 = 8 x 64)
  int qt = bid & 15, h = (bid >> 4) & 15, b = bid >> 8;
  int qbase = b * 2048 + qt * 128 + wid * 64;  // Q-block A: +0..31, B: +32..63
  int hc = h * 64;
  short8 qfrA[4], qfrB[4];
#pragma unroll
  for (int ds = 0; ds < 4; ++ds) {
    short8 rawA = *(const short8*)(Kb + (size_t)(qbase + ql) * 1024 + hc + ds * 16 + half * 8);
    short8 rawB =
        *(const short8*)(Kb + (size_t)(qbase + 32 + ql) * 1024 + hc + ds * 16 + half * 8);
    short8 qa, qb2;
#pragma unroll
    for (int j = 0; j < 8; ++j) {
      qa[j] = (short)f2b(b2f((u16)rawA[j]) * S2);
      qb2[j] = (short)f2b(b2f((u16)rawB[j]) * S2);
    }
    qfrA[ds] = qa;
    qfrB[ds] = qb2;
  }
  const short8 ones = {0x3F80, 0x3F80, 0x3F80, 0x3F80, 0x3F80, 0x3F80, 0x3F80, 0x3F80};
  f32x16 accA0 = {}, accA1 = {}, accAs = {};
  f32x16 accB0 = {}, accB1 = {}, accBs = {};
  int srow = lane >> 3;
  int scol = ((lane & 7) << 4) ^ (srow << 4);
  const char* Kbase = (const char*)Kb + (size_t)(b * 2048) * 2048 + hc * 2;
  const char* Vbase = (const char*)Kt + (size_t)((b * 16 + h) * 64) * 4096;

  // 2 waves split the 8 row-groups of each of K and V (r11-proven arrangement)
  auto stage = [&](char* buf, int kt) {
    const char* kp = Kbase + (size_t)(kt * 64) * 2048;
    const char* vp = Vbase + (size_t)(kt * 128);
    char* lk = buf;
    char* lv = buf + 8192;
#pragma unroll
    for (int j = 0; j < 4; ++j) {
      int grp = j * 2 + wid;  // 0..7
      int row = grp * 8 + srow;
      gload16(kp + (size_t)row * 2048 + scol, lk + grp * 8 * 128);
      gload16(vp + (size_t)row * 4096 + scol, lv + grp * 8 * 128);
    }
  };

  auto softmax_pack = [&](const f32x16& s0, const f32x16& s1, short8 pa[4]) {
    float p[32];
#pragma unroll
    for (int i = 0; i < 16; ++i) p[i] = __builtin_amdgcn_exp2f(s0[i]);
#pragma unroll
    for (int i = 0; i < 16; ++i) p[16 + i] = __builtin_amdgcn_exp2f(s1[i]);
    u32 w0[8], w1[8];
#pragma unroll
    for (int g = 0; g < 8; ++g) {
      int idx = (g >> 2) * 16 + (g & 3) * 4;
      w0[g] = cvtpk(p[idx], p[idx + 1]);
      w1[g] = cvtpk(p[idx + 2], p[idx + 3]);
    }
#pragma unroll
    for (int ks = 0; ks < 4; ++ks) {
      u32 a0 = w0[2 * ks], b0 = w0[2 * ks + 1];
      u32 a1 = w1[2 * ks], b1 = w1[2 * ks + 1];
      asm volatile("v_permlane32_swap_b32 %0, %1" : "+v"(a0), "+v"(b0));
      asm volatile("v_permlane32_swap_b32 %0, %1" : "+v"(a1), "+v"(b1));
      uint4 words = {a0, a1, b0, b1};
      pa[ks] = __builtin_bit_cast(short8, words);
    }
  };

  stage(kv[0], 0);
  for (int kt = 0; kt < 32; ++kt) {
    asm volatile("s_waitcnt vmcnt(0) lgkmcnt(0)" ::: "memory");
    barrier_fenced();
    if (kt + 1 < 32) stage(kv[(kt + 1) & 1], kt + 1);
    const char* lk = kv[kt & 1];
    const char* lv = lk + 8192;
    // shared K fragments
    short8 kf[2][4];
#pragma unroll
    for (int kb = 0; kb < 2; ++kb)
#pragma unroll
      for (int ds = 0; ds < 4; ++ds) {
        int row = kb * 32 + ql;
        kf[kb][ds] = *(const short8*)(lk + row * 128 + ((ds * 32 + half * 16) ^ ((row & 7) << 4)));
      }
    // QK for both Q-blocks (independent chains)
    f32x16 sA0 = {}, sA1 = {}, sB0 = {}, sB1 = {};
    __builtin_amdgcn_s_setprio(1);
#pragma unroll
    for (int ds = 0; ds < 4; ++ds) {
      sA0 = __builtin_amdgcn_mfma_f32_32x32x16_bf16(kf[0][ds], qfrA[ds], sA0, 0, 0, 0);
      sB0 = __builtin_amdgcn_mfma_f32_32x32x16_bf16(kf[0][ds], qfrB[ds], sB0, 0, 0, 0);
      sA1 = __builtin_amdgcn_mfma_f32_32x32x16_bf16(kf[1][ds], qfrA[ds], sA1, 0, 0, 0);
      sB1 = __builtin_amdgcn_mfma_f32_32x32x16_bf16(kf[1][ds], qfrB[ds], sB1, 0, 0, 0);
    }
    __builtin_amdgcn_s_setprio(0);
    // softmax+pack, both blocks (independent chains interleave)
    short8 paA[4], paB[4];
    softmax_pack(sA0, sA1, paA);
    softmax_pack(sB0, sB1, paB);
    // shared V fragments
    short8 vf0[4], vf1[4];
#pragma unroll
    for (int ks = 0; ks < 4; ++ks) {
      int row0 = ql, row1 = 32 + ql;
      vf0[ks] = *(const short8*)(lv + row0 * 128 + ((ks * 32 + half * 16) ^ ((row0 & 7) << 4)));
      vf1[ks] = *(const short8*)(lv + row1 * 128 + ((ks * 32 + half * 16) ^ ((row1 & 7) << 4)));
    }
    // PV + row-sums, both blocks
    __builtin_amdgcn_s_setprio(1);
#pragma unroll
    for (int ks = 0; ks < 4; ++ks) {
      accA0 = __builtin_amdgcn_mfma_f32_32x32x16_bf16(paA[ks], vf0[ks], accA0, 0, 0, 0);
      accB0 = __builtin_amdgcn_mfma_f32_32x32x16_bf16(paB[ks], vf0[ks], accB0, 0, 0, 0);
      accA1 = __builtin_amdgcn_mfma_f32_32x32x16_bf16(paA[ks], vf1[ks], accA1, 0, 0, 0);
      accB1 = __builtin_amdgcn_mfma_f32_32x32x16_bf16(paB[ks], vf1[ks], accB1, 0, 0, 0);
      accAs = __builtin_amdgcn_mfma_f32_32x32x16_bf16(paA[ks], ones, accAs, 0, 0, 0);
      accBs = __builtin_amdgcn_mfma_f32_32x32x16_bf16(paB[ks], ones, accBs, 0, 0, 0);
    }
    __builtin_amdgcn_s_setprio(0);
  }
#pragma unroll
  for (int reg = 0; reg < 16; ++reg) {
    int ridx = (reg & 3) + 8 * (reg >> 2) + 4 * half;
    int growA = qbase + ridx;
    int growB = qbase + 32 + ridx;
    float ivA = __builtin_amdgcn_rcpf(accAs[reg]);
    float ivB = __builtin_amdgcn_rcpf(accBs[reg]);
    AO[(size_t)growA * 1024 + hc + ql] = f2b(accA0[reg] * ivA);
    AO[(size_t)growA * 1024 + hc + 32 + ql] = f2b(accA1[reg] * ivA);
    AO[(size_t)growB * 1024 + hc + ql] = f2b(accB0[reg] * ivB);
    AO[(size_t)growB * 1024 + hc + 32 + ql] = f2b(accB1[reg] * ivB);
  }
}

// ---------------- launch ----------------

extern "C" void kernel_launch(void* const* d_in, const int* in_sizes, int n_in, void* d_out,
                              int out_size, void* d_ws, size_t ws_size, hipStream_t stream) {
  const float* x = (const float*)d_in[0];
  const float* W_attn = (const float*)d_in[1];
  const float* b_attn = (const float*)d_in[2];
  const float* W_proj = (const float*)d_in[3];
  const float* b_proj = (const float*)d_in[4];
  float* out = (float*)d_out;
  char* ws = (char*)d_ws;
  u16* xb = (u16*)(ws);
  u16* Kb = (u16*)(ws + 8388608);
  u16* Kt = (u16*)(ws + 16777216);
  u16* Wkt = (u16*)(ws + 25165824);
  u16* Wpt = (u16*)(ws + 27262976);

  prep<<<6144, 256, 0, stream>>>((const float4*)x, (uint2*)xb, W_attn, Wkt, W_proj, Wpt);
  gemm_bias<0><<<1024, 256, 0, stream>>>(xb, Wkt, b_attn + 1024, (void*)Kb, Kt, 4096, 1024, 1024);
  u16* AO = xb;
  flash_attn<<<512, 128, 0, stream>>>(Kb, Kt, AO);
  gemm_bias<1><<<1024, 256, 0, stream>>>(AO, Wpt, b_proj, (void*)out, nullptr, 4096, 1024, 1024);
}

// Round 17
// 94.442 us; speedup vs baseline: 1.1614x; 1.0287x over previous
//
#include <hip/hip_runtime.h>
#include <hip/hip_bf16.h>

typedef __attribute__((ext_vector_type(8))) short short8;
typedef __attribute__((ext_vector_type(4))) float f32x4;
typedef __attribute__((ext_vector_type(16))) float f32x16;
typedef unsigned short u16;
typedef unsigned int u32;

static __device__ __forceinline__ u16 f2b(float f) {
  __hip_bfloat16 h = __float2bfloat16(f);
  return __builtin_bit_cast(u16, h);
}
static __device__ __forceinline__ float b2f(u16 v) {
  return __builtin_bit_cast(float, ((u32)v) << 16);
}
static __device__ __forceinline__ u32 pk2(float lo, float hi) {
  return (u32)f2b(lo) | ((u32)f2b(hi) << 16);
}
static __device__ __forceinline__ u32 cvtpk(float lo, float hi) {
  u32 r;
  asm("v_cvt_pk_bf16_f32 %0, %1, %2" : "=v"(r) : "v"(lo), "v"(hi));
  return r;
}

static __device__ __forceinline__ void gload16(const void* g, void* l) {
  __builtin_amdgcn_global_load_lds((const __attribute__((address_space(1))) void*)g,
                                   (__attribute__((address_space(3))) void*)l, 16, 0, 0);
}

// Raw s_barrier has no compiler memory fence; add zero-cost scheduler+IR fences.
static __device__ __forceinline__ void barrier_fenced() {
  __builtin_amdgcn_sched_barrier(0);
  asm volatile("" ::: "memory");
  __builtin_amdgcn_s_barrier();
  __builtin_amdgcn_sched_barrier(0);
  asm volatile("" ::: "memory");
}

// ---------------- prep: W_attn K-slice transpose | W_proj transpose (weights only) -------
// x->bf16 conversion is fused into gemm0's A-staging (saves the 16MB xb round trip).
__global__ __launch_bounds__(256) void prep(const float* __restrict__ W_attn,
                                            u16* __restrict__ Wkt,
                                            const float* __restrict__ W_proj,
                                            u16* __restrict__ Wpt) {
  __shared__ u16 tile[32][33];
  int bid = blockIdx.x, t = threadIdx.x;
  const float* in;
  u16* out;
  int in_rs, col_off, blk;
  if (bid < 1024) {
    in = W_attn; out = Wkt; in_rs = 3072; col_off = 1024; blk = bid;
  } else {
    in = W_proj; out = Wpt; in_rs = 1024; col_off = 0; blk = bid - 1024;
  }
  int tx = t & 31, ty = t >> 5;
  int r0 = (blk >> 5) * 32, c0 = (blk & 31) * 32;
#pragma unroll
  for (int i = 0; i < 4; ++i) {
    int r = r0 + ty + i * 8;
    tile[ty + i * 8][tx] = f2b(in[(size_t)r * in_rs + col_off + c0 + tx]);
  }
  __syncthreads();
#pragma unroll
  for (int i = 0; i < 4; ++i) {
    int c = c0 + ty + i * 8;
    out[(size_t)c * 1024 + r0 + tx] = tile[tx][ty + i * 8];
  }
}

// ---------------- GEMM: C[M][N] = A[M][K] * Bt[N][K]^T + bias ----------------
// 64x64 tile, 4 waves (2x2), BK=64, double-buffered 32KB LDS, grid 1024, XCD chunking.
// MODE 0: A = f32 x, reg-staged with fused bf16 conversion (write-side swizzle reproduces
//         the gload_lds LDS image: LDS[row][s] = global[row][s ^ (row&7)]); bf16 C +
//         fused per-head K transpose.
// MODE 1: A = bf16 via global_load_lds; f32 C.
template <int MODE>
__global__ __launch_bounds__(256) void gemm_bias(const void* __restrict__ Ap,
                                                 const u16* __restrict__ Bt,
                                                 const float* __restrict__ bias,
                                                 void* __restrict__ Cp, u16* __restrict__ Ktp,
                                                 int M, int N, int K) {
  __shared__ char lds[2][16384];  // per buf: A 64x128B | B 64x128B
  int tid = threadIdx.x, lane = tid & 63, wid = tid >> 6;
  int lr = lane & 15, lh = lane >> 4;
  int rb = blockIdx.x;
  int bid = (rb & 7) * 128 + (rb >> 3);  // XCD chunking (1024 = 8 x 128)
  int m0 = (bid >> 4) << 6, n0 = (bid & 15) << 6;
  int wm = wid >> 1, wn = wid & 1;
  f32x4 acc[2][2] = {};
  int srow = lane >> 3;
  int scol = ((lane & 7) << 4) ^ (srow << 4);
  const char* Ab = (const char*)Ap;     // MODE 1: bf16 rows
  const float* Xf = (const float*)Ap;   // MODE 0: f32 rows
  const char* Bb = (const char*)Bt;
  const int NT = K >> 6;

  auto stage = [&](char* buf, int k0) {
    char* lA = buf;
    char* lB = buf + 8192;
#pragma unroll
    for (int j = 0; j < 2; ++j) {
      int rg = wid * 16 + j * 8;
      if (MODE == 0) {
        int row = m0 + rg + srow;
        const float* xs = Xf + (size_t)row * K + k0 + (lane & 7) * 8;
        float4 a0 = *(const float4*)xs;
        float4 a1 = *(const float4*)(xs + 4);
        uint4 wds;
        wds.x = cvtpk(a0.x, a0.y);
        wds.y = cvtpk(a0.z, a0.w);
        wds.z = cvtpk(a1.x, a1.y);
        wds.w = cvtpk(a1.z, a1.w);
        *(uint4*)(lA + (rg + srow) * 128 + (((lane & 7) ^ srow) << 4)) = wds;
      } else {
        gload16(Ab + ((size_t)(m0 + rg + srow) * K + k0) * 2 + scol, lA + rg * 128);
      }
      gload16(Bb + ((size_t)(n0 + rg + srow) * K + k0) * 2 + scol, lB + rg * 128);
    }
  };

  stage(lds[0], 0);
  for (int t = 0; t < NT; ++t) {
    asm volatile("s_waitcnt vmcnt(0) lgkmcnt(0)" ::: "memory");
    barrier_fenced();
    if (t + 1 < NT) stage(lds[(t + 1) & 1], (t + 1) << 6);
    char* lA = lds[t & 1];
    char* lB = lA + 8192;
    short8 af[2][2], bfr[2][2];
#pragma unroll
    for (int mi = 0; mi < 2; ++mi)
#pragma unroll
      for (int ks = 0; ks < 2; ++ks) {
        int row = wm * 32 + mi * 16 + lr;
        af[mi][ks] = *(const short8*)(lA + row * 128 + ((ks * 64 + lh * 16) ^ ((row & 7) << 4)));
      }
#pragma unroll
    for (int ni = 0; ni < 2; ++ni)
#pragma unroll
      for (int ks = 0; ks < 2; ++ks) {
        int row = wn * 32 + ni * 16 + lr;
        bfr[ni][ks] = *(const short8*)(lB + row * 128 + ((ks * 64 + lh * 16) ^ ((row & 7) << 4)));
      }
    __builtin_amdgcn_s_setprio(1);
#pragma unroll
    for (int ks = 0; ks < 2; ++ks)
#pragma unroll
      for (int mi = 0; mi < 2; ++mi)
#pragma unroll
        for (int ni = 0; ni < 2; ++ni)
          acc[mi][ni] = __builtin_amdgcn_mfma_f32_16x16x32_bf16(af[mi][ks], bfr[ni][ks],
                                                                acc[mi][ni], 0, 0, 0);
    __builtin_amdgcn_s_setprio(0);
  }
#pragma unroll
  for (int mi = 0; mi < 2; ++mi)
#pragma unroll
    for (int ni = 0; ni < 2; ++ni) {
      int col = n0 + wn * 32 + ni * 16 + lr;
      float bz = bias[col];
      int row0 = m0 + wm * 32 + mi * 16 + lh * 4;
      if (MODE == 1) {
#pragma unroll
        for (int r = 0; r < 4; ++r)
          ((float*)Cp)[(size_t)(row0 + r) * N + col] = acc[mi][ni][r] + bz;
      } else {
        ushort4 q;
        u16* qa = (u16*)&q;
#pragma unroll
        for (int r = 0; r < 4; ++r) {
          u16 v = f2b(acc[mi][ni][r] + bz);
          qa[r] = v;
          ((u16*)Cp)[(size_t)(row0 + r) * N + col] = v;
        }
        *(ushort4*)(Ktp + ((size_t)((row0 >> 11) * 1024 + col)) * 2048 + (row0 & 2047)) = q;
      }
    }
}

// ---------------- flash attention: pair-tile phases (r10/r13 proven, 53.6us) --------------
__global__ __launch_bounds__(256) void flash_attn(const u16* __restrict__ Kb,
                                                  const u16* __restrict__ Kt,
                                                  u16* __restrict__ AO) {
  __shared__ char kv[2][32768];  // per buf: 2 x (K [64k][128B] | V [64d][128B])
  const float S2 = 0.125f * 1.44269504088896340736f;
  int tid = threadIdx.x, lane = tid & 63, wid = tid >> 6;
  int ql = lane & 31, half = lane >> 5;
  int rb = blockIdx.x;
  int bid = (rb & 7) * 64 + (rb >> 3);  // XCD chunking
  int qb = bid & 15, h = (bid >> 4) & 15, b = bid >> 8;
  int qbase = b * 2048 + qb * 128 + wid * 32;
  int hc = h * 64;
  short8 qfr[4];
#pragma unroll
  for (int ds = 0; ds < 4; ++ds) {
    short8 raw = *(const short8*)(Kb + (size_t)(qbase + ql) * 1024 + hc + ds * 16 + half * 8);
    short8 q;
#pragma unroll
    for (int j = 0; j < 8; ++j) q[j] = (short)f2b(b2f((u16)raw[j]) * S2);
    qfr[ds] = q;
  }
  const short8 ones = {0x3F80, 0x3F80, 0x3F80, 0x3F80, 0x3F80, 0x3F80, 0x3F80, 0x3F80};
  f32x16 acc0 = {}, acc1 = {}, accs = {};
  int srow = lane >> 3;
  int scol = ((lane & 7) << 4) ^ (srow << 4);
  const char* Kbase = (const char*)Kb + (size_t)(b * 2048) * 2048 + hc * 2;
  const char* Vbase = (const char*)Kt + (size_t)((b * 16 + h) * 64) * 4096;

  auto stage_pair = [&](char* buf, int pt) {  // stages tiles 2pt, 2pt+1
#pragma unroll
    for (int tt = 0; tt < 2; ++tt) {
      int kt = 2 * pt + tt;
      const char* kp = Kbase + (size_t)(kt * 64) * 2048;
      const char* vp = Vbase + (size_t)(kt * 128);
      char* lk = buf + tt * 16384;
      char* lv = lk + 8192;
#pragma unroll
      for (int j = 0; j < 2; ++j) {
        int row = wid * 8 + j * 32 + srow;
        gload16(kp + (size_t)row * 2048 + scol, lk + (wid * 8 + j * 32) * 128);
        gload16(vp + (size_t)row * 4096 + scol, lv + (wid * 8 + j * 32) * 128);
      }
    }
  };

  auto read_kf = [&](const char* lk, short8 kf[2][4]) {
#pragma unroll
    for (int kb = 0; kb < 2; ++kb)
#pragma unroll
      for (int ds = 0; ds < 4; ++ds) {
        int row = kb * 32 + ql;
        kf[kb][ds] = *(const short8*)(lk + row * 128 + ((ds * 32 + half * 16) ^ ((row & 7) << 4)));
      }
  };
  auto read_vf = [&](const char* lv, short8 vf0[4], short8 vf1[4]) {
#pragma unroll
    for (int ks = 0; ks < 4; ++ks) {
      int row0 = ql, row1 = 32 + ql;
      vf0[ks] = *(const short8*)(lv + row0 * 128 + ((ks * 32 + half * 16) ^ ((row0 & 7) << 4)));
      vf1[ks] = *(const short8*)(lv + row1 * 128 + ((ks * 32 + half * 16) ^ ((row1 & 7) << 4)));
    }
  };
  auto softmax_pack = [&](const f32x16& s0, const f32x16& s1, short8 pa[4]) {
    float p[32];
#pragma unroll
    for (int i = 0; i < 16; ++i) p[i] = __builtin_amdgcn_exp2f(s0[i]);
#pragma unroll
    for (int i = 0; i < 16; ++i) p[16 + i] = __builtin_amdgcn_exp2f(s1[i]);
    u32 w0[8], w1[8];
#pragma unroll
    for (int g = 0; g < 8; ++g) {
      int idx = (g >> 2) * 16 + (g & 3) * 4;
      w0[g] = cvtpk(p[idx], p[idx + 1]);
      w1[g] = cvtpk(p[idx + 2], p[idx + 3]);
    }
#pragma unroll
    for (int ks = 0; ks < 4; ++ks) {
      u32 a0 = w0[2 * ks], b0 = w0[2 * ks + 1];
      u32 a1 = w1[2 * ks], b1 = w1[2 * ks + 1];
      asm volatile("v_permlane32_swap_b32 %0, %1" : "+v"(a0), "+v"(b0));
      asm volatile("v_permlane32_swap_b32 %0, %1" : "+v"(a1), "+v"(b1));
      uint4 words = {a0, a1, b0, b1};
      pa[ks] = __builtin_bit_cast(short8, words);
    }
  };

  stage_pair(kv[0], 0);
  for (int pt = 0; pt < 16; ++pt) {
    asm volatile("s_waitcnt vmcnt(0) lgkmcnt(0)" ::: "memory");
    barrier_fenced();
    if (pt + 1 < 16) stage_pair(kv[(pt + 1) & 1], pt + 1);
    const char* lkA = kv[pt & 1];
    const char* lvA = lkA + 8192;
    const char* lkB = lkA + 16384;
    const char* lvB = lkB + 8192;
    // ---- tile A: QK ----
    short8 kfA[2][4];
    read_kf(lkA, kfA);
    f32x16 s0 = {}, s1 = {};
    __builtin_amdgcn_s_setprio(1);
#pragma unroll
    for (int ds = 0; ds < 4; ++ds) {
      s0 = __builtin_amdgcn_mfma_f32_32x32x16_bf16(kfA[0][ds], qfr[ds], s0, 0, 0, 0);
      s1 = __builtin_amdgcn_mfma_f32_32x32x16_bf16(kfA[1][ds], qfr[ds], s1, 0, 0, 0);
    }
    __builtin_amdgcn_s_setprio(0);
    short8 vfA0[4], vfA1[4];
    read_vf(lvA, vfA0, vfA1);  // latency hides under exp2/pack A
    short8 paA[4];
    softmax_pack(s0, s1, paA);
    // ---- issue tile B K reads early: latency hides under PV-A ----
    short8 kfB[2][4];
    read_kf(lkB, kfB);
    // ---- PV-A (reg-only) ----
    __builtin_amdgcn_s_setprio(1);
#pragma unroll
    for (int ks = 0; ks < 4; ++ks) {
      acc0 = __builtin_amdgcn_mfma_f32_32x32x16_bf16(paA[ks], vfA0[ks], acc0, 0, 0, 0);
      acc1 = __builtin_amdgcn_mfma_f32_32x32x16_bf16(paA[ks], vfA1[ks], acc1, 0, 0, 0);
      accs = __builtin_amdgcn_mfma_f32_32x32x16_bf16(paA[ks], ones, accs, 0, 0, 0);
    }
    __builtin_amdgcn_s_setprio(0);
    // ---- tile B ----
    f32x16 t0 = {}, t1 = {};
    __builtin_amdgcn_s_setprio(1);
#pragma unroll
    for (int ds = 0; ds < 4; ++ds) {
      t0 = __builtin_amdgcn_mfma_f32_32x32x16_bf16(kfB[0][ds], qfr[ds], t0, 0, 0, 0);
      t1 = __builtin_amdgcn_mfma_f32_32x32x16_bf16(kfB[1][ds], qfr[ds], t1, 0, 0, 0);
    }
    __builtin_amdgcn_s_setprio(0);
    short8 vfB0[4], vfB1[4];
    read_vf(lvB, vfB0, vfB1);
    short8 paB[4];
    softmax_pack(t0, t1, paB);
    __builtin_amdgcn_s_setprio(1);
#pragma unroll
    for (int ks = 0; ks < 4; ++ks) {
      acc0 = __builtin_amdgcn_mfma_f32_32x32x16_bf16(paB[ks], vfB0[ks], acc0, 0, 0, 0);
      acc1 = __builtin_amdgcn_mfma_f32_32x32x16_bf16(paB[ks], vfB1[ks], acc1, 0, 0, 0);
      accs = __builtin_amdgcn_mfma_f32_32x32x16_bf16(paB[ks], ones, accs, 0, 0, 0);
    }
    __builtin_amdgcn_s_setprio(0);
  }
#pragma unroll
  for (int reg = 0; reg < 16; ++reg) {
    int ridx = (reg & 3) + 8 * (reg >> 2) + 4 * half;
    float iv = __builtin_amdgcn_rcpf(accs[reg]);
    int grow = qbase + ridx;
    AO[(size_t)grow * 1024 + hc + ql] = f2b(acc0[reg] * iv);
    AO[(size_t)grow * 1024 + hc + 32 + ql] = f2b(acc1[reg] * iv);
  }
}

// ---------------- launch ----------------

extern "C" void kernel_launch(void* const* d_in, const int* in_sizes, int n_in, void* d_out,
                              int out_size, void* d_ws, size_t ws_size, hipStream_t stream) {
  const float* x = (const float*)d_in[0];
  const float* W_attn = (const float*)d_in[1];
  const float* b_attn = (const float*)d_in[2];
  const float* W_proj = (const float*)d_in[3];
  const float* b_proj = (const float*)d_in[4];
  float* out = (float*)d_out;
  char* ws = (char*)d_ws;
  u16* AO = (u16*)(ws);                  // 8.4MB: flash output (x no longer staged here)
  u16* Kb = (u16*)(ws + 8388608);
  u16* Kt = (u16*)(ws + 16777216);
  u16* Wkt = (u16*)(ws + 25165824);
  u16* Wpt = (u16*)(ws + 27262976);

  prep<<<2048, 256, 0, stream>>>(W_attn, Wkt, W_proj, Wpt);
  // K = bf16(x)*Wk + bk -> Kb (row-major) AND Kt (per-head transposed); x converted in-staging
  gemm_bias<0><<<1024, 256, 0, stream>>>((const void*)x, Wkt, b_attn + 1024, (void*)Kb, Kt,
                                         4096, 1024, 1024);
  flash_attn<<<512, 256, 0, stream>>>(Kb, Kt, AO);
  gemm_bias<1><<<1024, 256, 0, stream>>>((const void*)AO, Wpt, b_proj, (void*)out, nullptr,
                                         4096, 1024, 1024);
}

// Round 18
// 88.932 us; speedup vs baseline: 1.2333x; 1.0620x over previous
//
#include <hip/hip_runtime.h>
#include <hip/hip_bf16.h>

typedef __attribute__((ext_vector_type(8))) short short8;
typedef __attribute__((ext_vector_type(4))) float f32x4;
typedef __attribute__((ext_vector_type(16))) float f32x16;
typedef unsigned short u16;
typedef unsigned int u32;

static __device__ __forceinline__ u16 f2b(float f) {
  __hip_bfloat16 h = __float2bfloat16(f);
  return __builtin_bit_cast(u16, h);
}
static __device__ __forceinline__ float b2f(u16 v) {
  return __builtin_bit_cast(float, ((u32)v) << 16);
}
static __device__ __forceinline__ u32 pk2(float lo, float hi) {
  return (u32)f2b(lo) | ((u32)f2b(hi) << 16);
}
static __device__ __forceinline__ u32 cvtpk(float lo, float hi) {
  u32 r;
  asm("v_cvt_pk_bf16_f32 %0, %1, %2" : "=v"(r) : "v"(lo), "v"(hi));
  return r;
}

static __device__ __forceinline__ void gload16(const void* g, void* l) {
  __builtin_amdgcn_global_load_lds((const __attribute__((address_space(1))) void*)g,
                                   (__attribute__((address_space(3))) void*)l, 16, 0, 0);
}

// Raw s_barrier has no compiler memory fence; add zero-cost scheduler+IR fences.
static __device__ __forceinline__ void barrier_fenced() {
  __builtin_amdgcn_sched_barrier(0);
  asm volatile("" ::: "memory");
  __builtin_amdgcn_s_barrier();
  __builtin_amdgcn_sched_barrier(0);
  asm volatile("" ::: "memory");
}

// ---------------- merged prep: x->bf16 | W_attn K-slice transpose | W_proj transpose ------
// Converting x to bf16 ONCE here is load-bearing: gemm0's A-panel is re-read by all 16
// n-blocks (128MB of L2 reads at bf16; r17's fused f32 path doubled that and regressed).
__global__ __launch_bounds__(256) void prep(const float4* __restrict__ x4,
                                            uint2* __restrict__ xb,
                                            const float* __restrict__ W_attn,
                                            u16* __restrict__ Wkt,
                                            const float* __restrict__ W_proj,
                                            u16* __restrict__ Wpt) {
  __shared__ u16 tile[32][33];
  int bid = blockIdx.x, t = threadIdx.x;
  if (bid < 4096) {
    int i = bid * 256 + t;
    float4 v = x4[i];
    uint2 o;
    o.x = pk2(v.x, v.y);
    o.y = pk2(v.z, v.w);
    xb[i] = o;
    return;
  }
  const float* in;
  u16* out;
  int in_rs, col_off, blk;
  if (bid < 5120) {
    in = W_attn; out = Wkt; in_rs = 3072; col_off = 1024; blk = bid - 4096;
  } else {
    in = W_proj; out = Wpt; in_rs = 1024; col_off = 0; blk = bid - 5120;
  }
  int tx = t & 31, ty = t >> 5;
  int r0 = (blk >> 5) * 32, c0 = (blk & 31) * 32;
#pragma unroll
  for (int i = 0; i < 4; ++i) {
    int r = r0 + ty + i * 8;
    tile[ty + i * 8][tx] = f2b(in[(size_t)r * in_rs + col_off + c0 + tx]);
  }
  __syncthreads();
#pragma unroll
  for (int i = 0; i < 4; ++i) {
    int c = c0 + ty + i * 8;
    out[(size_t)c * 1024 + r0 + tx] = tile[tx][ty + i * 8];
  }
}

// ---------------- GEMM: C[M][N] = A[M][K] * Bt[N][K]^T + bias (r13 proven) ----------------
// 64x64 tile, 4 waves (2x2), BK=64, double-buffered 32KB LDS, grid 1024 (4 blocks/CU),
// stage-after-barrier + vmcnt(0) drain, XCD chunking for B-panel L2 residency.
// MODE 0: bf16 C + fused per-head K transpose. MODE 1: f32 C.
template <int MODE>
__global__ __launch_bounds__(256) void gemm_bias(const u16* __restrict__ A,
                                                 const u16* __restrict__ Bt,
                                                 const float* __restrict__ bias,
                                                 void* __restrict__ Cp, u16* __restrict__ Ktp,
                                                 int M, int N, int K) {
  __shared__ char lds[2][16384];  // per buf: A 64x128B | B 64x128B
  int tid = threadIdx.x, lane = tid & 63, wid = tid >> 6;
  int lr = lane & 15, lh = lane >> 4;
  int rb = blockIdx.x;
  int bid = (rb & 7) * 128 + (rb >> 3);  // XCD chunking (1024 = 8 x 128)
  int m0 = (bid >> 4) << 6, n0 = (bid & 15) << 6;
  int wm = wid >> 1, wn = wid & 1;
  f32x4 acc[2][2] = {};
  int srow = lane >> 3;
  int scol = ((lane & 7) << 4) ^ (srow << 4);
  const char* Ab = (const char*)A;
  const char* Bb = (const char*)Bt;
  const int NT = K >> 6;

  auto stage = [&](char* buf, int k0) {
    char* lA = buf;
    char* lB = buf + 8192;
#pragma unroll
    for (int j = 0; j < 2; ++j) {
      int rg = wid * 16 + j * 8;
      gload16(Ab + ((size_t)(m0 + rg + srow) * K + k0) * 2 + scol, lA + rg * 128);
      gload16(Bb + ((size_t)(n0 + rg + srow) * K + k0) * 2 + scol, lB + rg * 128);
    }
  };

  stage(lds[0], 0);
  for (int t = 0; t < NT; ++t) {
    asm volatile("s_waitcnt vmcnt(0) lgkmcnt(0)" ::: "memory");
    barrier_fenced();
    if (t + 1 < NT) stage(lds[(t + 1) & 1], (t + 1) << 6);
    char* lA = lds[t & 1];
    char* lB = lA + 8192;
    short8 af[2][2], bfr[2][2];
#pragma unroll
    for (int mi = 0; mi < 2; ++mi)
#pragma unroll
      for (int ks = 0; ks < 2; ++ks) {
        int row = wm * 32 + mi * 16 + lr;
        af[mi][ks] = *(const short8*)(lA + row * 128 + ((ks * 64 + lh * 16) ^ ((row & 7) << 4)));
      }
#pragma unroll
    for (int ni = 0; ni < 2; ++ni)
#pragma unroll
      for (int ks = 0; ks < 2; ++ks) {
        int row = wn * 32 + ni * 16 + lr;
        bfr[ni][ks] = *(const short8*)(lB + row * 128 + ((ks * 64 + lh * 16) ^ ((row & 7) << 4)));
      }
    __builtin_amdgcn_s_setprio(1);
#pragma unroll
    for (int ks = 0; ks < 2; ++ks)
#pragma unroll
      for (int mi = 0; mi < 2; ++mi)
#pragma unroll
        for (int ni = 0; ni < 2; ++ni)
          acc[mi][ni] = __builtin_amdgcn_mfma_f32_16x16x32_bf16(af[mi][ks], bfr[ni][ks],
                                                                acc[mi][ni], 0, 0, 0);
    __builtin_amdgcn_s_setprio(0);
  }
#pragma unroll
  for (int mi = 0; mi < 2; ++mi)
#pragma unroll
    for (int ni = 0; ni < 2; ++ni) {
      int col = n0 + wn * 32 + ni * 16 + lr;
      float bz = bias[col];
      int row0 = m0 + wm * 32 + mi * 16 + lh * 4;
      if (MODE == 1) {
#pragma unroll
        for (int r = 0; r < 4; ++r)
          ((float*)Cp)[(size_t)(row0 + r) * N + col] = acc[mi][ni][r] + bz;
      } else {
        ushort4 q;
        u16* qa = (u16*)&q;
#pragma unroll
        for (int r = 0; r < 4; ++r) {
          u16 v = f2b(acc[mi][ni][r] + bz);
          qa[r] = v;
          ((u16*)Cp)[(size_t)(row0 + r) * N + col] = v;
        }
        *(ushort4*)(Ktp + ((size_t)((row0 >> 11) * 1024 + col)) * 2048 + (row0 & 2047)) = q;
      }
    }
}

// ---------------- flash attention: pair-tile phases (r10/r13 proven, 53.6us) --------------
__global__ __launch_bounds__(256) void flash_attn(const u16* __restrict__ Kb,
                                                  const u16* __restrict__ Kt,
                                                  u16* __restrict__ AO) {
  __shared__ char kv[2][32768];  // per buf: 2 x (K [64k][128B] | V [64d][128B])
  const float S2 = 0.125f * 1.44269504088896340736f;
  int tid = threadIdx.x, lane = tid & 63, wid = tid >> 6;
  int ql = lane & 31, half = lane >> 5;
  int rb = blockIdx.x;
  int bid = (rb & 7) * 64 + (rb >> 3);  // XCD chunking
  int qb = bid & 15, h = (bid >> 4) & 15, b = bid >> 8;
  int qbase = b * 2048 + qb * 128 + wid * 32;
  int hc = h * 64;
  short8 qfr[4];
#pragma unroll
  for (int ds = 0; ds < 4; ++ds) {
    short8 raw = *(const short8*)(Kb + (size_t)(qbase + ql) * 1024 + hc + ds * 16 + half * 8);
    short8 q;
#pragma unroll
    for (int j = 0; j < 8; ++j) q[j] = (short)f2b(b2f((u16)raw[j]) * S2);
    qfr[ds] = q;
  }
  const short8 ones = {0x3F80, 0x3F80, 0x3F80, 0x3F80, 0x3F80, 0x3F80, 0x3F80, 0x3F80};
  f32x16 acc0 = {}, acc1 = {}, accs = {};
  int srow = lane >> 3;
  int scol = ((lane & 7) << 4) ^ (srow << 4);
  const char* Kbase = (const char*)Kb + (size_t)(b * 2048) * 2048 + hc * 2;
  const char* Vbase = (const char*)Kt + (size_t)((b * 16 + h) * 64) * 4096;

  auto stage_pair = [&](char* buf, int pt) {  // stages tiles 2pt, 2pt+1
#pragma unroll
    for (int tt = 0; tt < 2; ++tt) {
      int kt = 2 * pt + tt;
      const char* kp = Kbase + (size_t)(kt * 64) * 2048;
      const char* vp = Vbase + (size_t)(kt * 128);
      char* lk = buf + tt * 16384;
      char* lv = lk + 8192;
#pragma unroll
      for (int j = 0; j < 2; ++j) {
        int row = wid * 8 + j * 32 + srow;
        gload16(kp + (size_t)row * 2048 + scol, lk + (wid * 8 + j * 32) * 128);
        gload16(vp + (size_t)row * 4096 + scol, lv + (wid * 8 + j * 32) * 128);
      }
    }
  };

  auto read_kf = [&](const char* lk, short8 kf[2][4]) {
#pragma unroll
    for (int kb = 0; kb < 2; ++kb)
#pragma unroll
      for (int ds = 0; ds < 4; ++ds) {
        int row = kb * 32 + ql;
        kf[kb][ds] = *(const short8*)(lk + row * 128 + ((ds * 32 + half * 16) ^ ((row & 7) << 4)));
      }
  };
  auto read_vf = [&](const char* lv, short8 vf0[4], short8 vf1[4]) {
#pragma unroll
    for (int ks = 0; ks < 4; ++ks) {
      int row0 = ql, row1 = 32 + ql;
      vf0[ks] = *(const short8*)(lv + row0 * 128 + ((ks * 32 + half * 16) ^ ((row0 & 7) << 4)));
      vf1[ks] = *(const short8*)(lv + row1 * 128 + ((ks * 32 + half * 16) ^ ((row1 & 7) << 4)));
    }
  };
  auto softmax_pack = [&](const f32x16& s0, const f32x16& s1, short8 pa[4]) {
    float p[32];
#pragma unroll
    for (int i = 0; i < 16; ++i) p[i] = __builtin_amdgcn_exp2f(s0[i]);
#pragma unroll
    for (int i = 0; i < 16; ++i) p[16 + i] = __builtin_amdgcn_exp2f(s1[i]);
    u32 w0[8], w1[8];
#pragma unroll
    for (int g = 0; g < 8; ++g) {
      int idx = (g >> 2) * 16 + (g & 3) * 4;
      w0[g] = cvtpk(p[idx], p[idx + 1]);
      w1[g] = cvtpk(p[idx + 2], p[idx + 3]);
    }
#pragma unroll
    for (int ks = 0; ks < 4; ++ks) {
      u32 a0 = w0[2 * ks], b0 = w0[2 * ks + 1];
      u32 a1 = w1[2 * ks], b1 = w1[2 * ks + 1];
      asm volatile("v_permlane32_swap_b32 %0, %1" : "+v"(a0), "+v"(b0));
      asm volatile("v_permlane32_swap_b32 %0, %1" : "+v"(a1), "+v"(b1));
      uint4 words = {a0, a1, b0, b1};
      pa[ks] = __builtin_bit_cast(short8, words);
    }
  };

  stage_pair(kv[0], 0);
  for (int pt = 0; pt < 16; ++pt) {
    asm volatile("s_waitcnt vmcnt(0) lgkmcnt(0)" ::: "memory");
    barrier_fenced();
    if (pt + 1 < 16) stage_pair(kv[(pt + 1) & 1], pt + 1);
    const char* lkA = kv[pt & 1];
    const char* lvA = lkA + 8192;
    const char* lkB = lkA + 16384;
    const char* lvB = lkB + 8192;
    // ---- tile A: QK ----
    short8 kfA[2][4];
    read_kf(lkA, kfA);
    f32x16 s0 = {}, s1 = {};
    __builtin_amdgcn_s_setprio(1);
#pragma unroll
    for (int ds = 0; ds < 4; ++ds) {
      s0 = __builtin_amdgcn_mfma_f32_32x32x16_bf16(kfA[0][ds], qfr[ds], s0, 0, 0, 0);
      s1 = __builtin_amdgcn_mfma_f32_32x32x16_bf16(kfA[1][ds], qfr[ds], s1, 0, 0, 0);
    }
    __builtin_amdgcn_s_setprio(0);
    short8 vfA0[4], vfA1[4];
    read_vf(lvA, vfA0, vfA1);  // latency hides under exp2/pack A
    short8 paA[4];
    softmax_pack(s0, s1, paA);
    // ---- issue tile B K reads early: latency hides under PV-A ----
    short8 kfB[2][4];
    read_kf(lkB, kfB);
    // ---- PV-A (reg-only) ----
    __builtin_amdgcn_s_setprio(1);
#pragma unroll
    for (int ks = 0; ks < 4; ++ks) {
      acc0 = __builtin_amdgcn_mfma_f32_32x32x16_bf16(paA[ks], vfA0[ks], acc0, 0, 0, 0);
      acc1 = __builtin_amdgcn_mfma_f32_32x32x16_bf16(paA[ks], vfA1[ks], acc1, 0, 0, 0);
      accs = __builtin_amdgcn_mfma_f32_32x32x16_bf16(paA[ks], ones, accs, 0, 0, 0);
    }
    __builtin_amdgcn_s_setprio(0);
    // ---- tile B ----
    f32x16 t0 = {}, t1 = {};
    __builtin_amdgcn_s_setprio(1);
#pragma unroll
    for (int ds = 0; ds < 4; ++ds) {
      t0 = __builtin_amdgcn_mfma_f32_32x32x16_bf16(kfB[0][ds], qfr[ds], t0, 0, 0, 0);
      t1 = __builtin_amdgcn_mfma_f32_32x32x16_bf16(kfB[1][ds], qfr[ds], t1, 0, 0, 0);
    }
    __builtin_amdgcn_s_setprio(0);
    short8 vfB0[4], vfB1[4];
    read_vf(lvB, vfB0, vfB1);
    short8 paB[4];
    softmax_pack(t0, t1, paB);
    __builtin_amdgcn_s_setprio(1);
#pragma unroll
    for (int ks = 0; ks < 4; ++ks) {
      acc0 = __builtin_amdgcn_mfma_f32_32x32x16_bf16(paB[ks], vfB0[ks], acc0, 0, 0, 0);
      acc1 = __builtin_amdgcn_mfma_f32_32x32x16_bf16(paB[ks], vfB1[ks], acc1, 0, 0, 0);
      accs = __builtin_amdgcn_mfma_f32_32x32x16_bf16(paB[ks], ones, accs, 0, 0, 0);
    }
    __builtin_amdgcn_s_setprio(0);
  }
#pragma unroll
  for (int reg = 0; reg < 16; ++reg) {
    int ridx = (reg & 3) + 8 * (reg >> 2) + 4 * half;
    float iv = __builtin_amdgcn_rcpf(accs[reg]);
    int grow = qbase + ridx;
    AO[(size_t)grow * 1024 + hc + ql] = f2b(acc0[reg] * iv);
    AO[(size_t)grow * 1024 + hc + 32 + ql] = f2b(acc1[reg] * iv);
  }
}

// ---------------- launch ----------------

extern "C" void kernel_launch(void* const* d_in, const int* in_sizes, int n_in, void* d_out,
                              int out_size, void* d_ws, size_t ws_size, hipStream_t stream) {
  const float* x = (const float*)d_in[0];
  const float* W_attn = (const float*)d_in[1];
  const float* b_attn = (const float*)d_in[2];
  const float* W_proj = (const float*)d_in[3];
  const float* b_proj = (const float*)d_in[4];
  float* out = (float*)d_out;
  char* ws = (char*)d_ws;
  u16* xb = (u16*)(ws);
  u16* Kb = (u16*)(ws + 8388608);
  u16* Kt = (u16*)(ws + 16777216);
  u16* Wkt = (u16*)(ws + 25165824);
  u16* Wpt = (u16*)(ws + 27262976);

  prep<<<6144, 256, 0, stream>>>((const float4*)x, (uint2*)xb, W_attn, Wkt, W_proj, Wpt);
  gemm_bias<0><<<1024, 256, 0, stream>>>(xb, Wkt, b_attn + 1024, (void*)Kb, Kt, 4096, 1024, 1024);
  u16* AO = xb;
  flash_attn<<<512, 256, 0, stream>>>(Kb, Kt, AO);
  gemm_bias<1><<<1024, 256, 0, stream>>>(AO, Wpt, b_proj, (void*)out, nullptr, 4096, 1024, 1024);
}